// Round 10
// baseline (103.846 us; speedup 1.0000x reference)
//
#include <hip/hip_runtime.h>
#include <math.h>

// Problem constants (fixed by setup_inputs)
#define U_TOTAL 40000
#define N_PTS   32
#define C_IN    9
#define C_OUT   64
#define NPOINTS (U_TOTAL * N_PTS)          // 1,280,000 points
#define TILE_PTS    256                    // points per tile
#define TILE_FLOATS (TILE_PTS * C_IN)      // 2304 floats = 9216 B
#define NTILES  (NPOINTS / TILE_PTS)       // 5000 (exact)
#define GRID_S  1024                       // stats-pass grid
#define GRID_M  2048                       // main-pass grid
#define NSUM    54                         // 9 first + 45 tri second moments
#define EPSV    1e-3f

typedef float    f32x2  __attribute__((ext_vector_type(2)));
typedef float    f32x16 __attribute__((ext_vector_type(16)));
typedef short    short8 __attribute__((ext_vector_type(8)));
typedef unsigned u32x4  __attribute__((ext_vector_type(4)));

__device__ __forceinline__ unsigned pk_bf16(float lo, float hi) {
    unsigned r;
    asm("v_cvt_pk_bf16_f32 %0, %1, %2" : "=v"(r) : "v"(lo), "v"(hi));
    return r;
}

// ---------------------------------------------------------------------------
// Pass 1 (stats): streaming moment reduction. Stats of x = X.W^T are linear
// in the input moments: sum_x[o] = w_o . Sp, sum_x2[o] = w_o^T S w_o with
// Sp = sum(p) (9) and S = sum(p p^T) (45 tri). So this pass never touches W.
// COALESCED: float4 loads (lane-contiguous 1 KB/wave-instr -> few address
// segments, unlike the 36B-stride scatter that walled rounds 5-7 at 2.2TB/s),
// LDS transpose, per-thread one point per tile (9 ds_read_b32, bank
// 9t mod 32 = permutation -> conflict-free). Issue-early prefetch of the
// next tile's regs before computing the current one. Moments accumulate in
// 54 registers (static indices only); block-reduce via 3 shfl levels + LDS;
// one atomicAdd per moment per block into sums[] (zeroed by memsetAsync).
// ---------------------------------------------------------------------------
__global__ __launch_bounds__(256)
void pfn_stats(const float* __restrict__ in, float* __restrict__ sums)
{
    __shared__ float lbuf[TILE_FLOATS];
    const int tid = threadIdx.x;

    float acc[NSUM];
#pragma unroll
    for (int v = 0; v < NSUM; ++v) acc[v] = 0.f;

    int tile = blockIdx.x;
    const float4* src = (const float4*)(in + (size_t)tile * TILE_FLOATS);
    float4 v0 = src[tid], v1 = src[tid + 256], v2 = {};
    if (tid < 64) v2 = src[tid + 512];

    while (tile < NTILES) {
        __syncthreads();                       // prev readers done
        ((float4*)lbuf)[tid]       = v0;
        ((float4*)lbuf)[tid + 256] = v1;
        if (tid < 64) ((float4*)lbuf)[tid + 512] = v2;
        __syncthreads();

        const int nt = tile + GRID_S;
        if (nt < NTILES) {                     // prefetch next tile's regs
            const float4* ns = (const float4*)(in + (size_t)nt * TILE_FLOATS);
            v0 = ns[tid]; v1 = ns[tid + 256];
            if (tid < 64) v2 = ns[tid + 512];
        }

        // this thread's point: floats [9*tid, 9*tid+9)
        float pv[C_IN];
        const float* p = lbuf + tid * C_IN;
#pragma unroll
        for (int k = 0; k < C_IN; ++k) pv[k] = p[k];
#pragma unroll
        for (int k = 0; k < C_IN; ++k) acc[k] += pv[k];
        {
            int idx = C_IN;                    // static under full unroll
#pragma unroll
            for (int i = 0; i < C_IN; ++i)
#pragma unroll
                for (int j = i; j < C_IN; ++j) {
                    acc[idx] = fmaf(pv[i], pv[j], acc[idx]);
                    ++idx;
                }
        }
        tile = nt;
    }

    // fold 8 consecutive lanes, park 32 rows in LDS, column-sum, one atomic
#pragma unroll
    for (int v = 0; v < NSUM; ++v) {
        acc[v] += __shfl_xor(acc[v], 1);
        acc[v] += __shfl_xor(acc[v], 2);
        acc[v] += __shfl_xor(acc[v], 4);
    }
    __syncthreads();                           // lbuf reuse
    if ((tid & 7) == 0) {
        float* row = lbuf + (tid >> 3) * NSUM;
#pragma unroll
        for (int v = 0; v < NSUM; ++v) row[v] = acc[v];
    }
    __syncthreads();
    if (tid < NSUM) {
        float s = 0.f;
#pragma unroll
        for (int r = 0; r < 32; ++r) s += lbuf[r * NSUM + tid];
        atomicAdd(&sums[tid], s);
    }
}

// ---------------------------------------------------------------------------
// Pass 2 (main): with stats known, fold BN INTO the weights: W' = scale*W
// (bf16 B-fragment), bias b' = beta - mean*scale added AFTER the max (bias
// is uniform per column so max(D)+b == max(D+b); relu(max)==max(relu)).
// out = relu(max_n p.W'_o + b'_o) written ONCE -- kernels B and C deleted.
// Same coalesced float4 -> LDS-transpose staging as pass 1; reads should be
// L3-warm from pass 1. Per tile (8 u): wave w computes u = 2w, 2w+1 via the
// verified A-frag layout (g=lane>>5 holds k{4g..4g+3}+k8(g=0); k>=9 zero),
// 2x mfma_32x32x16_bf16 from zero-acc, packed-max D reduction, 256 B/wave
// contiguous store.
// ---------------------------------------------------------------------------
__global__ __launch_bounds__(256)
void pfn_main(const float* __restrict__ in, const float* __restrict__ Wg,
              const float* __restrict__ gamma, const float* __restrict__ beta,
              const float* __restrict__ sums, float* __restrict__ out)
{
    __shared__ float lbuf[TILE_FLOATS];
    const int tid  = threadIdx.x;
    const int lane = tid & 63;
    const int w    = tid >> 6;
    const int col  = lane & 31;
    const int g    = lane >> 5;

    // ---- BN prep from moments (per thread, for channels col and 32+col)
    float wa[C_IN], wb[C_IN];
#pragma unroll
    for (int k = 0; k < C_IN; ++k) {
        wa[k] = Wg[(size_t)col * C_IN + k];
        wb[k] = Wg[(size_t)(32 + col) * C_IN + k];
    }
    float spa = 0.f, spb = 0.f;
#pragma unroll
    for (int k = 0; k < C_IN; ++k) {
        spa = fmaf(wa[k], sums[k], spa);
        spb = fmaf(wb[k], sums[k], spb);
    }
    float e2a = 0.f, e2b = 0.f;
    {
        int idx = C_IN;
#pragma unroll
        for (int i = 0; i < C_IN; ++i)
#pragma unroll
            for (int j = i; j < C_IN; ++j) {
                const float s = sums[idx]; ++idx;
                const float f = (i == j) ? 1.f : 2.f;
                e2a = fmaf(f * wa[i] * wa[j], s, e2a);
                e2b = fmaf(f * wb[i] * wb[j], s, e2b);
            }
    }
    const float invM  = 1.f / (float)NPOINTS;
    const float mean_a = spa * invM,  mean_b = spb * invM;
    const float var_a  = fmaf(-mean_a, mean_a, e2a * invM);
    const float var_b  = fmaf(-mean_b, mean_b, e2b * invM);
    const float sc_a = gamma[col]      * __frsqrt_rn(var_a + EPSV);
    const float sc_b = gamma[32 + col] * __frsqrt_rn(var_b + EPSV);
    const float b_a  = beta[col]      - mean_a * sc_a;
    const float b_b  = beta[32 + col] - mean_b * sc_b;

    // ---- B fragments from W' = scale*W (verified K-layout)
    u32x4 b0, b1;
    b0[0] = pk_bf16(sc_a * wa[4 * g], sc_a * wa[4 * g + 1]);
    b0[1] = pk_bf16(sc_a * wa[4 * g + 2], sc_a * wa[4 * g + 3]);
    b0[2] = pk_bf16(g ? 0.f : sc_a * wa[8], 0.f);
    b0[3] = 0u;
    b1[0] = pk_bf16(sc_b * wb[4 * g], sc_b * wb[4 * g + 1]);
    b1[1] = pk_bf16(sc_b * wb[4 * g + 2], sc_b * wb[4 * g + 3]);
    b1[2] = pk_bf16(g ? 0.f : sc_b * wb[8], 0.f);
    b1[3] = 0u;
    const short8 B0v = __builtin_bit_cast(short8, b0);
    const short8 B1v = __builtin_bit_cast(short8, b1);

    int tile = blockIdx.x;
    const float4* src = (const float4*)(in + (size_t)tile * TILE_FLOATS);
    float4 v0 = src[tid], v1 = src[tid + 256], v2 = {};
    if (tid < 64) v2 = src[tid + 512];

    while (tile < NTILES) {
        __syncthreads();
        ((float4*)lbuf)[tid]       = v0;
        ((float4*)lbuf)[tid + 256] = v1;
        if (tid < 64) ((float4*)lbuf)[tid + 512] = v2;
        __syncthreads();

        const int nt = tile + GRID_M;
        if (nt < NTILES) {
            const float4* ns = (const float4*)(in + (size_t)nt * TILE_FLOATS);
            v0 = ns[tid]; v1 = ns[tid + 256];
            if (tid < 64) v2 = ns[tid + 512];
        }

#pragma unroll
        for (int t = 0; t < 2; ++t) {
            const int uloc = 2 * w + t;
            const float* p = lbuf + (size_t)(uloc * N_PTS + col) * C_IN;
            u32x4 a;
            a[0] = pk_bf16(p[4 * g], p[4 * g + 1]);
            a[1] = pk_bf16(p[4 * g + 2], p[4 * g + 3]);
            a[2] = pk_bf16(g ? 0.f : p[8], 0.f);
            a[3] = 0u;
            const short8 Av = __builtin_bit_cast(short8, a);
            const f32x16 z = {};
            float m0, m1;
            {
                f32x16 d = __builtin_amdgcn_mfma_f32_32x32x16_bf16(Av, B0v, z, 0, 0, 0);
                f32x2 mx = {d[0], d[1]};
#pragma unroll
                for (int i = 1; i < 8; ++i) {
                    f32x2 q = {d[2 * i], d[2 * i + 1]};
                    mx = __builtin_elementwise_max(mx, q);
                }
                m0 = fmaxf(mx.x, mx.y);
                m0 = fmaxf(m0, __shfl_xor(m0, 32));   // fold other 16 rows
            }
            {
                f32x16 d = __builtin_amdgcn_mfma_f32_32x32x16_bf16(Av, B1v, z, 0, 0, 0);
                f32x2 mx = {d[0], d[1]};
#pragma unroll
                for (int i = 1; i < 8; ++i) {
                    f32x2 q = {d[2 * i], d[2 * i + 1]};
                    mx = __builtin_elementwise_max(mx, q);
                }
                m1 = fmaxf(mx.x, mx.y);
                m1 = fmaxf(m1, __shfl_xor(m1, 32));
            }
            // lane -> channel lane (g? 32+col : col); bias after max, then relu
            const float y = (g ? m1 + b_b : m0 + b_a);
            out[(size_t)(tile * 8 + uloc) * C_OUT + lane] = fmaxf(y, 0.f);
        }
        tile = nt;
    }
}

extern "C" void kernel_launch(void* const* d_in, const int* in_sizes, int n_in,
                              void* d_out, int out_size, void* d_ws, size_t ws_size,
                              hipStream_t stream)
{
    const float* in    = (const float*)d_in[0];
    const float* Wg    = (const float*)d_in[1];
    const float* gamma = (const float*)d_in[2];
    const float* beta  = (const float*)d_in[3];
    float* out  = (float*)d_out;
    float* sums = (float*)d_ws;              // 64 floats (54 used)

    hipMemsetAsync(sums, 0, 64 * sizeof(float), stream);
    pfn_stats<<<GRID_S, 256, 0, stream>>>(in, sums);
    pfn_main <<<GRID_M, 256, 0, stream>>>(in, Wg, gamma, beta, sums, out);
}

// Round 11
// 53.852 us; speedup vs baseline: 1.9284x; 1.9284x over previous
//
#include <hip/hip_runtime.h>
#include <math.h>

// Problem constants (fixed by setup_inputs)
#define U_TOTAL 40000
#define N_PTS   32
#define C_IN    9
#define C_OUT   64
#define NPOINTS (U_TOTAL * N_PTS)          // 1,280,000 points
#define TILE_PTS    256                    // points per tile
#define TILE_FLOATS (TILE_PTS * C_IN)      // 2304 floats = 9216 B
#define NTILES  (NPOINTS / TILE_PTS)       // 5000 (exact)
#define GRID_S  1024                       // stats-pass grid
#define GRID_M  2048                       // main-pass grid
#define NSUM    54                         // 9 first + 45 tri second moments
#define EPSV    1e-3f

typedef float    f32x2  __attribute__((ext_vector_type(2)));
typedef float    f32x16 __attribute__((ext_vector_type(16)));
typedef short    short8 __attribute__((ext_vector_type(8)));
typedef unsigned u32x4  __attribute__((ext_vector_type(4)));

__device__ __forceinline__ unsigned pk_bf16(float lo, float hi) {
    unsigned r;
    asm("v_cvt_pk_bf16_f32 %0, %1, %2" : "=v"(r) : "v"(lo), "v"(hi));
    return r;
}

// Triangular moment index for the pair (i,j), i<=j, as a compile-time
// expression of unroll-constant i,j: pairs before row i = 9i - i(i-1)/2.
#define TRI_IDX(i, j) (C_IN + 9 * (i) - ((i) * ((i) - 1)) / 2 + ((j) - (i)))

// ---------------------------------------------------------------------------
// Pass 1 (stats): streaming moment reduction. Stats of x = X.W^T are linear
// in the input moments: sum_x[o] = w_o . Sp, sum_x2[o] = w_o^T S w_o with
// Sp = sum(p) (9) and S = sum(p p^T) (45 tri) -- never touches W.
// ROUND-10 BUG FIXED: the triangular accumulation used an inner loop with an
// i-dependent lower bound + a running idx -> clang couldn't fully unroll ->
// acc[54] demoted to scratch (VGPR_Count 44, WRITE_SIZE 235 MB, 103 us).
// Now a full 9x9 nest with CONSTANT trip counts and a compile-time j>=i
// guard; TRI_IDX(i,j) is an unroll-constant -> SROA keeps acc[] in VGPRs.
// launch_bounds(256,4) caps at 128 VGPR (~95 needed): no spill.
// COALESCED: float4 loads -> LDS transpose; per-thread one point per tile
// (9*tid mod 32 permutation -> <=2-way LDS banking, free). Next tile's regs
// prefetched before computing the current one. Block-reduce: 3 shfl levels,
// 32 rows to LDS, column-sum, one atomicAdd per moment (sums[] zeroed by
// hipMemsetAsync each call).
// ---------------------------------------------------------------------------
__global__ __launch_bounds__(256, 4)
void pfn_stats(const float* __restrict__ in, float* __restrict__ sums)
{
    __shared__ float lbuf[TILE_FLOATS];
    const int tid = threadIdx.x;

    float acc[NSUM];
#pragma unroll
    for (int v = 0; v < NSUM; ++v) acc[v] = 0.f;

    int tile = blockIdx.x;
    const float4* src = (const float4*)(in + (size_t)tile * TILE_FLOATS);
    float4 v0 = src[tid], v1 = src[tid + 256], v2 = {};
    if (tid < 64) v2 = src[tid + 512];

    while (tile < NTILES) {
        __syncthreads();                       // prev readers done
        ((float4*)lbuf)[tid]       = v0;
        ((float4*)lbuf)[tid + 256] = v1;
        if (tid < 64) ((float4*)lbuf)[tid + 512] = v2;
        __syncthreads();

        const int nt = tile + GRID_S;
        if (nt < NTILES) {                     // prefetch next tile's regs
            const float4* ns = (const float4*)(in + (size_t)nt * TILE_FLOATS);
            v0 = ns[tid]; v1 = ns[tid + 256];
            if (tid < 64) v2 = ns[tid + 512];
        }

        // this thread's point: floats [9*tid, 9*tid+9)
        float pv[C_IN];
        const float* p = lbuf + tid * C_IN;
#pragma unroll
        for (int k = 0; k < C_IN; ++k) pv[k] = p[k];
#pragma unroll
        for (int k = 0; k < C_IN; ++k) acc[k] += pv[k];
#pragma unroll
        for (int i = 0; i < C_IN; ++i)
#pragma unroll
            for (int j = 0; j < C_IN; ++j)
                if (j >= i)                     // compile-time guard
                    acc[TRI_IDX(i, j)] = fmaf(pv[i], pv[j], acc[TRI_IDX(i, j)]);
        tile = nt;
    }

    // fold 8 consecutive lanes, park 32 rows in LDS, column-sum, one atomic
#pragma unroll
    for (int v = 0; v < NSUM; ++v) {
        acc[v] += __shfl_xor(acc[v], 1);
        acc[v] += __shfl_xor(acc[v], 2);
        acc[v] += __shfl_xor(acc[v], 4);
    }
    __syncthreads();                           // lbuf reuse
    if ((tid & 7) == 0) {
        float* row = lbuf + (tid >> 3) * NSUM;
#pragma unroll
        for (int v = 0; v < NSUM; ++v) row[v] = acc[v];
    }
    __syncthreads();
    if (tid < NSUM) {
        float s = 0.f;
#pragma unroll
        for (int r = 0; r < 32; ++r) s += lbuf[r * NSUM + tid];
        atomicAdd(&sums[tid], s);
    }
}

// ---------------------------------------------------------------------------
// Pass 2 (main): with stats known, fold BN INTO the weights: W' = scale*W
// (bf16 B-fragment), bias b' = beta - mean*scale added AFTER the max (bias
// is uniform per column so max(D)+b == max(D+b); relu(max)==max(relu)).
// out = relu(max_n p.W'_o + b'_o) written ONCE. Same coalesced float4 ->
// LDS-transpose staging; reads L3-warm from pass 1. Prologue triangular
// reconstruction uses the same constant-trip 9x9 nest (keeps wa/wb in VGPRs).
// Per tile (8 u): wave w computes u = 2w, 2w+1 via the verified A-frag
// layout (g=lane>>5 holds k{4g..4g+3}+k8(g=0); k>=9 zero), 2x
// mfma_32x32x16_bf16 from zero-acc, packed-max D reduction, contiguous store.
// ---------------------------------------------------------------------------
__global__ __launch_bounds__(256, 4)
void pfn_main(const float* __restrict__ in, const float* __restrict__ Wg,
              const float* __restrict__ gamma, const float* __restrict__ beta,
              const float* __restrict__ sums, float* __restrict__ out)
{
    __shared__ float lbuf[TILE_FLOATS];
    const int tid  = threadIdx.x;
    const int lane = tid & 63;
    const int w    = tid >> 6;
    const int col  = lane & 31;
    const int g    = lane >> 5;

    // ---- BN prep from moments (per thread, for channels col and 32+col)
    float wa[C_IN], wb[C_IN];
#pragma unroll
    for (int k = 0; k < C_IN; ++k) {
        wa[k] = Wg[(size_t)col * C_IN + k];
        wb[k] = Wg[(size_t)(32 + col) * C_IN + k];
    }
    float spa = 0.f, spb = 0.f;
#pragma unroll
    for (int k = 0; k < C_IN; ++k) {
        spa = fmaf(wa[k], sums[k], spa);
        spb = fmaf(wb[k], sums[k], spb);
    }
    float e2a = 0.f, e2b = 0.f;
#pragma unroll
    for (int i = 0; i < C_IN; ++i)
#pragma unroll
        for (int j = 0; j < C_IN; ++j)
            if (j >= i) {
                const float s = sums[TRI_IDX(i, j)];
                const float f = (i == j) ? 1.f : 2.f;
                e2a = fmaf(f * wa[i] * wa[j], s, e2a);
                e2b = fmaf(f * wb[i] * wb[j], s, e2b);
            }
    const float invM  = 1.f / (float)NPOINTS;
    const float mean_a = spa * invM,  mean_b = spb * invM;
    const float var_a  = fmaf(-mean_a, mean_a, e2a * invM);
    const float var_b  = fmaf(-mean_b, mean_b, e2b * invM);
    const float sc_a = gamma[col]      * __frsqrt_rn(var_a + EPSV);
    const float sc_b = gamma[32 + col] * __frsqrt_rn(var_b + EPSV);
    const float b_a  = beta[col]      - mean_a * sc_a;
    const float b_b  = beta[32 + col] - mean_b * sc_b;

    // ---- B fragments from W' = scale*W (verified K-layout)
    u32x4 b0, b1;
    b0[0] = pk_bf16(sc_a * wa[4 * g], sc_a * wa[4 * g + 1]);
    b0[1] = pk_bf16(sc_a * wa[4 * g + 2], sc_a * wa[4 * g + 3]);
    b0[2] = pk_bf16(g ? 0.f : sc_a * wa[8], 0.f);
    b0[3] = 0u;
    b1[0] = pk_bf16(sc_b * wb[4 * g], sc_b * wb[4 * g + 1]);
    b1[1] = pk_bf16(sc_b * wb[4 * g + 2], sc_b * wb[4 * g + 3]);
    b1[2] = pk_bf16(g ? 0.f : sc_b * wb[8], 0.f);
    b1[3] = 0u;
    const short8 B0v = __builtin_bit_cast(short8, b0);
    const short8 B1v = __builtin_bit_cast(short8, b1);

    int tile = blockIdx.x;
    const float4* src = (const float4*)(in + (size_t)tile * TILE_FLOATS);
    float4 v0 = src[tid], v1 = src[tid + 256], v2 = {};
    if (tid < 64) v2 = src[tid + 512];

    while (tile < NTILES) {
        __syncthreads();
        ((float4*)lbuf)[tid]       = v0;
        ((float4*)lbuf)[tid + 256] = v1;
        if (tid < 64) ((float4*)lbuf)[tid + 512] = v2;
        __syncthreads();

        const int nt = tile + GRID_M;
        if (nt < NTILES) {
            const float4* ns = (const float4*)(in + (size_t)nt * TILE_FLOATS);
            v0 = ns[tid]; v1 = ns[tid + 256];
            if (tid < 64) v2 = ns[tid + 512];
        }

#pragma unroll
        for (int t = 0; t < 2; ++t) {
            const int uloc = 2 * w + t;
            const float* p = lbuf + (size_t)(uloc * N_PTS + col) * C_IN;
            u32x4 a;
            a[0] = pk_bf16(p[4 * g], p[4 * g + 1]);
            a[1] = pk_bf16(p[4 * g + 2], p[4 * g + 3]);
            a[2] = pk_bf16(g ? 0.f : p[8], 0.f);
            a[3] = 0u;
            const short8 Av = __builtin_bit_cast(short8, a);
            const f32x16 z = {};
            float m0, m1;
            {
                f32x16 d = __builtin_amdgcn_mfma_f32_32x32x16_bf16(Av, B0v, z, 0, 0, 0);
                f32x2 mx = {d[0], d[1]};
#pragma unroll
                for (int i = 1; i < 8; ++i) {
                    f32x2 q = {d[2 * i], d[2 * i + 1]};
                    mx = __builtin_elementwise_max(mx, q);
                }
                m0 = fmaxf(mx.x, mx.y);
                m0 = fmaxf(m0, __shfl_xor(m0, 32));   // fold other 16 rows
            }
            {
                f32x16 d = __builtin_amdgcn_mfma_f32_32x32x16_bf16(Av, B1v, z, 0, 0, 0);
                f32x2 mx = {d[0], d[1]};
#pragma unroll
                for (int i = 1; i < 8; ++i) {
                    f32x2 q = {d[2 * i], d[2 * i + 1]};
                    mx = __builtin_elementwise_max(mx, q);
                }
                m1 = fmaxf(mx.x, mx.y);
                m1 = fmaxf(m1, __shfl_xor(m1, 32));
            }
            // lane -> channel lane (g? 32+col : col); bias after max, then relu
            const float y = (g ? m1 + b_b : m0 + b_a);
            out[(size_t)(tile * 8 + uloc) * C_OUT + lane] = fmaxf(y, 0.f);
        }
        tile = nt;
    }
}

extern "C" void kernel_launch(void* const* d_in, const int* in_sizes, int n_in,
                              void* d_out, int out_size, void* d_ws, size_t ws_size,
                              hipStream_t stream)
{
    const float* in    = (const float*)d_in[0];
    const float* Wg    = (const float*)d_in[1];
    const float* gamma = (const float*)d_in[2];
    const float* beta  = (const float*)d_in[3];
    float* out  = (float*)d_out;
    float* sums = (float*)d_ws;              // 64 floats (54 used)

    hipMemsetAsync(sums, 0, 64 * sizeof(float), stream);
    pfn_stats<<<GRID_S, 256, 0, stream>>>(in, sums);
    pfn_main <<<GRID_M, 256, 0, stream>>>(in, Wg, gamma, beta, sums, out);
}

// Round 12
// 34.066 us; speedup vs baseline: 3.0484x; 1.5808x over previous
//
#include <hip/hip_runtime.h>
#include <math.h>

// Problem constants (fixed by setup_inputs)
#define U_TOTAL 40000
#define N_PTS   32
#define C_IN    9
#define C_OUT   64
#define NPOINTS (U_TOTAL * N_PTS)          // 1,280,000 points
#define TILE_PTS    256                    // points per tile
#define TILE_FLOATS (TILE_PTS * C_IN)      // 2304 floats = 9216 B
#define NTILES  (NPOINTS / TILE_PTS)       // 5000 (exact)
#define GRID_S  1024                       // stats-pass grid
#define GRID_M  2048                       // main-pass grid
#define NSUM    54                         // 9 first + 45 tri second moments
#define EPSV    1e-3f

typedef float    f32x2  __attribute__((ext_vector_type(2)));
typedef float    f32x16 __attribute__((ext_vector_type(16)));
typedef short    short8 __attribute__((ext_vector_type(8)));
typedef unsigned u32x4  __attribute__((ext_vector_type(4)));

__device__ __forceinline__ unsigned pk_bf16(float lo, float hi) {
    unsigned r;
    asm("v_cvt_pk_bf16_f32 %0, %1, %2" : "=v"(r) : "v"(lo), "v"(hi));
    return r;
}

// Triangular moment index for the pair (i,j), i<=j, as a compile-time
// expression of unroll-constant i,j: pairs before row i = 9i - i(i-1)/2.
#define TRI_IDX(i, j) (C_IN + 9 * (i) - ((i) * ((i) - 1)) / 2 + ((j) - (i)))

// ---------------------------------------------------------------------------
// Pass 1 (stats): streaming moment reduction. Stats of x = X.W^T are linear
// in the input moments: sum_x[o] = w_o . Sp, sum_x2[o] = w_o^T S w_o with
// Sp = sum(p) (9) and S = sum(p p^T) (45 tri) -- never touches W.
// Triangular accumulation as a constant-trip 9x9 nest with compile-time j>=i
// guard (round-10 scratch-demotion fix; acc[54] stays in VGPRs).
// ROUND-11 FIX: no atomics, no hipMemsetAsync -- the 256-B memset node
// replayed as a ~40 us fillBufferAligned (75% of total). Block-partials go
// to partials[54][1024] (fully overwritten every call -> deterministic);
// pfn_reduce54 folds them.
// COALESCED: float4 loads -> LDS transpose; per-thread one point per tile
// (9*tid mod 32 permutation -> <=2-way LDS banking, free). Next tile's regs
// prefetched before computing the current one.
// ---------------------------------------------------------------------------
__global__ __launch_bounds__(256, 4)
void pfn_stats(const float* __restrict__ in, float* __restrict__ partials)
{
    __shared__ float lbuf[TILE_FLOATS];
    const int tid = threadIdx.x;

    float acc[NSUM];
#pragma unroll
    for (int v = 0; v < NSUM; ++v) acc[v] = 0.f;

    int tile = blockIdx.x;
    const float4* src = (const float4*)(in + (size_t)tile * TILE_FLOATS);
    float4 v0 = src[tid], v1 = src[tid + 256], v2 = {};
    if (tid < 64) v2 = src[tid + 512];

    while (tile < NTILES) {
        __syncthreads();                       // prev readers done
        ((float4*)lbuf)[tid]       = v0;
        ((float4*)lbuf)[tid + 256] = v1;
        if (tid < 64) ((float4*)lbuf)[tid + 512] = v2;
        __syncthreads();

        const int nt = tile + GRID_S;
        if (nt < NTILES) {                     // prefetch next tile's regs
            const float4* ns = (const float4*)(in + (size_t)nt * TILE_FLOATS);
            v0 = ns[tid]; v1 = ns[tid + 256];
            if (tid < 64) v2 = ns[tid + 512];
        }

        // this thread's point: floats [9*tid, 9*tid+9)
        float pv[C_IN];
        const float* p = lbuf + tid * C_IN;
#pragma unroll
        for (int k = 0; k < C_IN; ++k) pv[k] = p[k];
#pragma unroll
        for (int k = 0; k < C_IN; ++k) acc[k] += pv[k];
#pragma unroll
        for (int i = 0; i < C_IN; ++i)
#pragma unroll
            for (int j = 0; j < C_IN; ++j)
                if (j >= i)                     // compile-time guard
                    acc[TRI_IDX(i, j)] = fmaf(pv[i], pv[j], acc[TRI_IDX(i, j)]);
        tile = nt;
    }

    // fold 8 consecutive lanes, park 32 rows in LDS, column-sum, one store
#pragma unroll
    for (int v = 0; v < NSUM; ++v) {
        acc[v] += __shfl_xor(acc[v], 1);
        acc[v] += __shfl_xor(acc[v], 2);
        acc[v] += __shfl_xor(acc[v], 4);
    }
    __syncthreads();                           // lbuf reuse
    if ((tid & 7) == 0) {
        float* row = lbuf + (tid >> 3) * NSUM;
#pragma unroll
        for (int v = 0; v < NSUM; ++v) row[v] = acc[v];
    }
    __syncthreads();
    if (tid < NSUM) {
        float s = 0.f;
#pragma unroll
        for (int r = 0; r < 32; ++r) s += lbuf[r * NSUM + tid];
        partials[(size_t)tid * GRID_S + blockIdx.x] = s;   // [54][1024]
    }
}

// ---------------------------------------------------------------------------
// Pass 1b: fold partials[54][1024] -> sums[54]. 54 blocks, each streams its
// contiguous 4 KB row. ~1-2 us; replaces the pathological memset+atomics.
// ---------------------------------------------------------------------------
__global__ __launch_bounds__(256)
void pfn_reduce54(const float* __restrict__ partials, float* __restrict__ sums)
{
    const int b = blockIdx.x;     // 0..53 (moment index)
    const int t = threadIdx.x;
    const float* row = partials + (size_t)b * GRID_S;
    float a = row[t] + row[t + 256] + row[t + 512] + row[t + 768];
#pragma unroll
    for (int s = 1; s <= 32; s <<= 1) a += __shfl_xor(a, s);
    __shared__ float r[4];
    if ((t & 63) == 0) r[t >> 6] = a;
    __syncthreads();
    if (t == 0) sums[b] = r[0] + r[1] + r[2] + r[3];
}

// ---------------------------------------------------------------------------
// Pass 2 (main): with stats known, fold BN INTO the weights: W' = scale*W
// (bf16 B-fragment), bias b' = beta - mean*scale added AFTER the max (bias
// is uniform per column so max(D)+b == max(D+b); relu(max)==max(relu)).
// out = relu(max_n p.W'_o + b'_o) written ONCE. Same coalesced float4 ->
// LDS-transpose staging; reads L3-warm from pass 1. Prologue triangular
// reconstruction uses the same constant-trip 9x9 nest (keeps wa/wb in VGPRs).
// Per tile (8 u): wave w computes u = 2w, 2w+1 via the verified A-frag
// layout (g=lane>>5 holds k{4g..4g+3}+k8(g=0); k>=9 zero), 2x
// mfma_32x32x16_bf16 from zero-acc, packed-max D reduction, contiguous store.
// ---------------------------------------------------------------------------
__global__ __launch_bounds__(256, 4)
void pfn_main(const float* __restrict__ in, const float* __restrict__ Wg,
              const float* __restrict__ gamma, const float* __restrict__ beta,
              const float* __restrict__ sums, float* __restrict__ out)
{
    __shared__ float lbuf[TILE_FLOATS];
    const int tid  = threadIdx.x;
    const int lane = tid & 63;
    const int w    = tid >> 6;
    const int col  = lane & 31;
    const int g    = lane >> 5;

    // ---- BN prep from moments (per thread, for channels col and 32+col)
    float wa[C_IN], wb[C_IN];
#pragma unroll
    for (int k = 0; k < C_IN; ++k) {
        wa[k] = Wg[(size_t)col * C_IN + k];
        wb[k] = Wg[(size_t)(32 + col) * C_IN + k];
    }
    float spa = 0.f, spb = 0.f;
#pragma unroll
    for (int k = 0; k < C_IN; ++k) {
        spa = fmaf(wa[k], sums[k], spa);
        spb = fmaf(wb[k], sums[k], spb);
    }
    float e2a = 0.f, e2b = 0.f;
#pragma unroll
    for (int i = 0; i < C_IN; ++i)
#pragma unroll
        for (int j = 0; j < C_IN; ++j)
            if (j >= i) {
                const float s = sums[TRI_IDX(i, j)];
                const float f = (i == j) ? 1.f : 2.f;
                e2a = fmaf(f * wa[i] * wa[j], s, e2a);
                e2b = fmaf(f * wb[i] * wb[j], s, e2b);
            }
    const float invM  = 1.f / (float)NPOINTS;
    const float mean_a = spa * invM,  mean_b = spb * invM;
    const float var_a  = fmaf(-mean_a, mean_a, e2a * invM);
    const float var_b  = fmaf(-mean_b, mean_b, e2b * invM);
    const float sc_a = gamma[col]      * __frsqrt_rn(var_a + EPSV);
    const float sc_b = gamma[32 + col] * __frsqrt_rn(var_b + EPSV);
    const float b_a  = beta[col]      - mean_a * sc_a;
    const float b_b  = beta[32 + col] - mean_b * sc_b;

    // ---- B fragments from W' = scale*W (verified K-layout)
    u32x4 b0, b1;
    b0[0] = pk_bf16(sc_a * wa[4 * g], sc_a * wa[4 * g + 1]);
    b0[1] = pk_bf16(sc_a * wa[4 * g + 2], sc_a * wa[4 * g + 3]);
    b0[2] = pk_bf16(g ? 0.f : sc_a * wa[8], 0.f);
    b0[3] = 0u;
    b1[0] = pk_bf16(sc_b * wb[4 * g], sc_b * wb[4 * g + 1]);
    b1[1] = pk_bf16(sc_b * wb[4 * g + 2], sc_b * wb[4 * g + 3]);
    b1[2] = pk_bf16(g ? 0.f : sc_b * wb[8], 0.f);
    b1[3] = 0u;
    const short8 B0v = __builtin_bit_cast(short8, b0);
    const short8 B1v = __builtin_bit_cast(short8, b1);

    int tile = blockIdx.x;
    const float4* src = (const float4*)(in + (size_t)tile * TILE_FLOATS);
    float4 v0 = src[tid], v1 = src[tid + 256], v2 = {};
    if (tid < 64) v2 = src[tid + 512];

    while (tile < NTILES) {
        __syncthreads();
        ((float4*)lbuf)[tid]       = v0;
        ((float4*)lbuf)[tid + 256] = v1;
        if (tid < 64) ((float4*)lbuf)[tid + 512] = v2;
        __syncthreads();

        const int nt = tile + GRID_M;
        if (nt < NTILES) {
            const float4* ns = (const float4*)(in + (size_t)nt * TILE_FLOATS);
            v0 = ns[tid]; v1 = ns[tid + 256];
            if (tid < 64) v2 = ns[tid + 512];
        }

#pragma unroll
        for (int t = 0; t < 2; ++t) {
            const int uloc = 2 * w + t;
            const float* p = lbuf + (size_t)(uloc * N_PTS + col) * C_IN;
            u32x4 a;
            a[0] = pk_bf16(p[4 * g], p[4 * g + 1]);
            a[1] = pk_bf16(p[4 * g + 2], p[4 * g + 3]);
            a[2] = pk_bf16(g ? 0.f : p[8], 0.f);
            a[3] = 0u;
            const short8 Av = __builtin_bit_cast(short8, a);
            const f32x16 z = {};
            float m0, m1;
            {
                f32x16 d = __builtin_amdgcn_mfma_f32_32x32x16_bf16(Av, B0v, z, 0, 0, 0);
                f32x2 mx = {d[0], d[1]};
#pragma unroll
                for (int i = 1; i < 8; ++i) {
                    f32x2 q = {d[2 * i], d[2 * i + 1]};
                    mx = __builtin_elementwise_max(mx, q);
                }
                m0 = fmaxf(mx.x, mx.y);
                m0 = fmaxf(m0, __shfl_xor(m0, 32));   // fold other 16 rows
            }
            {
                f32x16 d = __builtin_amdgcn_mfma_f32_32x32x16_bf16(Av, B1v, z, 0, 0, 0);
                f32x2 mx = {d[0], d[1]};
#pragma unroll
                for (int i = 1; i < 8; ++i) {
                    f32x2 q = {d[2 * i], d[2 * i + 1]};
                    mx = __builtin_elementwise_max(mx, q);
                }
                m1 = fmaxf(mx.x, mx.y);
                m1 = fmaxf(m1, __shfl_xor(m1, 32));
            }
            // lane -> channel lane (g? 32+col : col); bias after max, then relu
            const float y = (g ? m1 + b_b : m0 + b_a);
            out[(size_t)(tile * 8 + uloc) * C_OUT + lane] = fmaxf(y, 0.f);
        }
        tile = nt;
    }
}

extern "C" void kernel_launch(void* const* d_in, const int* in_sizes, int n_in,
                              void* d_out, int out_size, void* d_ws, size_t ws_size,
                              hipStream_t stream)
{
    const float* in    = (const float*)d_in[0];
    const float* Wg    = (const float*)d_in[1];
    const float* gamma = (const float*)d_in[2];
    const float* beta  = (const float*)d_in[3];
    float* out  = (float*)d_out;

    float* partials = (float*)d_ws;                    // 54 x 1024 floats
    float* sums     = partials + (size_t)NSUM * GRID_S; // 54 floats

    pfn_stats   <<<GRID_S, 256, 0, stream>>>(in, partials);
    pfn_reduce54<<<NSUM,   256, 0, stream>>>(partials, sums);
    pfn_main    <<<GRID_M, 256, 0, stream>>>(in, Wg, gamma, beta, sums, out);
}